// Round 1
// 161.025 us; speedup vs baseline: 1.0048x; 1.0048x over previous
//
#include <hip/hip_runtime.h>
#include <float.h>
#include <stdint.h>

#define EMB_DIM  300
#define MAX_LEN  128
#define HIDDEN   1000
#define NCLS     5
#define VOCAB_SZ 50000
#define KPAD     640     // 600 padded to 10*64
#define NPAD     1024    // 1000 padded to 16*64
#define EMBPAD   320     // 300 dims padded to 320 shorts = 640 B

typedef float    f32x4   __attribute__((ext_vector_type(4)));
typedef __bf16   bf16x8  __attribute__((ext_vector_type(8)));
typedef unsigned short ushort8v __attribute__((ext_vector_type(8)));

#define EMB_CHUNKS (VOCAB_SZ * (EMBPAD / 8))            // 2,000,000 chunks of 8 shorts
#define EMB_BLOCKS ((EMB_CHUNKS + 255) / 256)           // 7813

__device__ __forceinline__ unsigned short f2bf(float f) {
    union { float f; uint32_t u; } v; v.f = f;
    uint32_t u = v.u;
    return (unsigned short)((u + 0x7FFFu + ((u >> 16) & 1u)) >> 16);   // RNE
}
__device__ __forceinline__ float bf2f(unsigned short h) {
    union { uint32_t u; float f; } v; v.u = ((uint32_t)h) << 16;
    return v.f;
}

// ---------------------------------------------------------------------------
// prep_all: one dispatch for emb conversion + weight preps + out=b2 init.
//  blocks [0, embBlocks):               emb f32 -> embb bf16 [50000][320] (8 shorts/thread)
//  blocks [embBlocks, +640):            transpose W1 -> W1T bf16 [1024][640]
//  blocks [embBlocks+640, +20):         W2 -> W2T bf16 [5][1024]
//  blocks [embBlocks+660, +outBlocks):  out[m][c] = b2[c]   (gemm1p atomically adds)
// ---------------------------------------------------------------------------
__global__ __launch_bounds__(256) void prep_all(
    const float* __restrict__ emb, unsigned short* __restrict__ embb,
    const float* __restrict__ W1, unsigned short* __restrict__ Bt,
    const float* __restrict__ W2, unsigned short* __restrict__ W2t,
    const float* __restrict__ b2, float* __restrict__ out,
    int M, int embBlocks)
{
    __shared__ float t[32][33];
    const int blk = blockIdx.x;

    if (blk < embBlocks) {
        const int i = blk * 256 + threadIdx.x;        // chunk of 8 shorts (16 B)
        if (i >= EMB_CHUNKS) return;
        const int v  = i / 40;
        const int ch = i - v * 40;
        ushort8v o = {0, 0, 0, 0, 0, 0, 0, 0};
        if (ch < 38) {                                // dims [ch*8, ch*8+8)
            const float* src = emb + (size_t)v * EMB_DIM + ch * 8;
            const float4 f0 = *(const float4*)src;    // row base is 16B-aligned (300*4=1200)
            o[0] = f2bf(f0.x); o[1] = f2bf(f0.y); o[2] = f2bf(f0.z); o[3] = f2bf(f0.w);
            if (ch < 37) {
                const float4 f1 = *(const float4*)(src + 4);
                o[4] = f2bf(f1.x); o[5] = f2bf(f1.y); o[6] = f2bf(f1.z); o[7] = f2bf(f1.w);
            }                                         // ch==37: dims 300..303 stay 0 (pad)
        }
        *(ushort8v*)(embb + (size_t)v * EMBPAD + ch * 8) = o;
        return;
    }
    const int pb = blk - embBlocks;
    if (pb < 640) {
        // W1 transpose: pb -> (px, py) in (32, 20)
        const int px = pb & 31, py = pb >> 5;
        const int tx = threadIdx.x & 31, ty = threadIdx.x >> 5;   // 32 x 8
        const int n0 = px * 32, k0 = py * 32;
        #pragma unroll
        for (int i = 0; i < 4; ++i) {
            int k = k0 + ty + i * 8, n = n0 + tx;
            t[ty + i * 8][tx] = (k < 600 && n < HIDDEN) ? W1[(size_t)k * HIDDEN + n] : 0.f;
        }
        __syncthreads();
        #pragma unroll
        for (int i = 0; i < 4; ++i) {
            int n = n0 + ty + i * 8, k = k0 + tx;
            Bt[(size_t)n * KPAD + k] = f2bf(t[tx][ty + i * 8]);
        }
        return;
    }
    const int pc = pb - 640;
    if (pc < 20) {                                    // W2T: 20 blocks
        const int i = pc * 256 + threadIdx.x;         // [0, 5120)
        const int c = i >> 10, k = i & 1023;
        const float v = (k < HIDDEN) ? W2[(size_t)k * NCLS + c] : 0.f;
        W2t[(size_t)c * 1024 + k] = f2bf(v);
        return;
    }
    const int po = pc - 20;                           // out init
    const int oi = po * 256 + threadIdx.x;
    if (oi < M * NCLS) out[oi] = b2[oi % NCLS];
}

// ---------------------------------------------------------------------------
// pool_bf16: gather + masked avg/max over bf16 table -> rep bf16 [B][640].
// Indices pre-clamped into LDS; 4-deep unrolled gather for MLP.
// ---------------------------------------------------------------------------
__global__ __launch_bounds__(128) void pool_bf16(
    const int* __restrict__ x, const int* __restrict__ lengths,
    const unsigned short* __restrict__ embb, unsigned short* __restrict__ rep)
{
    const int b = blockIdx.x;
    const int t = threadIdx.x;

    __shared__ int sidx[MAX_LEN];
    {
        int v = x[b * MAX_LEN + t];
        sidx[t] = max(0, min(v, VOCAB_SZ - 1));
    }
    __syncthreads();

    unsigned short* rb = rep + (size_t)b * KPAD;

    if (t >= 75) {
        if (t < 85) {                      // zero pad cols 600..639
            ushort4 z = {0, 0, 0, 0};
            *(ushort4*)(rb + 600 + (t - 75) * 4) = z;
        }
        return;
    }

    int L = lengths[b];
    L = max(1, min(L, MAX_LEN));

    const int d = t * 4;
    const unsigned short* base = embb + d;
    float4 s  = {0.f, 0.f, 0.f, 0.f};
    float4 mx = {-FLT_MAX, -FLT_MAX, -FLT_MAX, -FLT_MAX};

    int i = 0;
    for (; i + 4 <= L; i += 4) {
        const ushort4 u0 = *(const ushort4*)(base + (size_t)sidx[i]     * EMBPAD);
        const ushort4 u1 = *(const ushort4*)(base + (size_t)sidx[i + 1] * EMBPAD);
        const ushort4 u2 = *(const ushort4*)(base + (size_t)sidx[i + 2] * EMBPAD);
        const ushort4 u3 = *(const ushort4*)(base + (size_t)sidx[i + 3] * EMBPAD);
        float a0 = bf2f(u0.x), a1 = bf2f(u0.y), a2 = bf2f(u0.z), a3 = bf2f(u0.w);
        float b0 = bf2f(u1.x), b1v = bf2f(u1.y), b2v = bf2f(u1.z), b3 = bf2f(u1.w);
        float c0 = bf2f(u2.x), c1 = bf2f(u2.y), c2 = bf2f(u2.z), c3 = bf2f(u2.w);
        float e0 = bf2f(u3.x), e1 = bf2f(u3.y), e2 = bf2f(u3.z), e3 = bf2f(u3.w);
        s.x += (a0 + b0) + (c0 + e0);
        s.y += (a1 + b1v) + (c1 + e1);
        s.z += (a2 + b2v) + (c2 + e2);
        s.w += (a3 + b3) + (c3 + e3);
        mx.x = fmaxf(mx.x, fmaxf(fmaxf(a0, b0), fmaxf(c0, e0)));
        mx.y = fmaxf(mx.y, fmaxf(fmaxf(a1, b1v), fmaxf(c1, e1)));
        mx.z = fmaxf(mx.z, fmaxf(fmaxf(a2, b2v), fmaxf(c2, e2)));
        mx.w = fmaxf(mx.w, fmaxf(fmaxf(a3, b3), fmaxf(c3, e3)));
    }
    for (; i < L; ++i) {
        const ushort4 u = *(const ushort4*)(base + (size_t)sidx[i] * EMBPAD);
        float a0 = bf2f(u.x), a1 = bf2f(u.y), a2 = bf2f(u.z), a3 = bf2f(u.w);
        s.x += a0; s.y += a1; s.z += a2; s.w += a3;
        mx.x = fmaxf(mx.x, a0); mx.y = fmaxf(mx.y, a1);
        mx.z = fmaxf(mx.z, a2); mx.w = fmaxf(mx.w, a3);
    }

    const float inv = 1.0f / (float)L;
    ushort4 av, mv;
    av.x = f2bf(s.x * inv); av.y = f2bf(s.y * inv);
    av.z = f2bf(s.z * inv); av.w = f2bf(s.w * inv);
    mv.x = f2bf(mx.x); mv.y = f2bf(mx.y); mv.z = f2bf(mx.z); mv.w = f2bf(mx.w);
    *(ushort4*)(rb + d)       = av;     // avg -> [0,300)
    *(ushort4*)(rb + 300 + d) = mv;     // max -> [300,600)
}

// ---------------------------------------------------------------------------
// pool_f32 (fallback if ws too small for the bf16 table).
// ---------------------------------------------------------------------------
__global__ __launch_bounds__(128) void pool_f32(
    const int* __restrict__ x, const int* __restrict__ lengths,
    const float* __restrict__ emb, unsigned short* __restrict__ rep)
{
    const int b = blockIdx.x;
    const int t = threadIdx.x;

    __shared__ int sidx[MAX_LEN];
    sidx[t] = x[b * MAX_LEN + t];
    __syncthreads();

    unsigned short* rb = rep + (size_t)b * KPAD;

    if (t >= 75) {
        if (t < 85) {
            ushort4 z = {0, 0, 0, 0};
            *(ushort4*)(rb + 600 + (t - 75) * 4) = z;
        }
        return;
    }

    int L = lengths[b];
    L = max(1, min(L, MAX_LEN));

    const int d = t * 4;
    float4 s  = {0.f, 0.f, 0.f, 0.f};
    float4 mx = {-FLT_MAX, -FLT_MAX, -FLT_MAX, -FLT_MAX};

    for (int i = 0; i < L; ++i) {
        int idx = max(0, min(sidx[i], VOCAB_SZ - 1));
        const float4 v = *(const float4*)(emb + (size_t)idx * EMB_DIM + d);
        s.x += v.x; s.y += v.y; s.z += v.z; s.w += v.w;
        mx.x = fmaxf(mx.x, v.x); mx.y = fmaxf(mx.y, v.y);
        mx.z = fmaxf(mx.z, v.z); mx.w = fmaxf(mx.w, v.w);
    }

    const float inv = 1.0f / (float)L;
    ushort4 av, mv;
    av.x = f2bf(s.x * inv); av.y = f2bf(s.y * inv);
    av.z = f2bf(s.z * inv); av.w = f2bf(s.w * inv);
    mv.x = f2bf(mx.x); mv.y = f2bf(mx.y); mv.z = f2bf(mx.z); mv.w = f2bf(mx.w);
    *(ushort4*)(rb + d)       = av;
    *(ushort4*)(rb + 300 + d) = mv;
}

// ---------------------------------------------------------------------------
// gemm1p: out[m][c] += sum over this block's n-slice of relu(rep@W1+b1)@W2.
// 128x128 tile, BK=64 (10 K-iters), m97 geometry: 4 waves, 64x64/wave,
// 4x4 16x16x32 frags, LDS 64KB dbuf, global_load_lds(16B).
// Fused epilogue: relu + W2, 16-lane butterfly over n, cross-wave combine
// in LDS, atomicAdd into out (pre-initialized to b2 by prep_all).
// ---------------------------------------------------------------------------
#define BM 128
#define BN 128
#define BK 64

__global__ __launch_bounds__(256, 2) void gemm1p(
    const unsigned short* __restrict__ A,    // rep  [M][640] bf16
    const unsigned short* __restrict__ Bt,   // W1T  [1024][640] bf16
    const float* __restrict__ bias,          // b1 [1000]
    const unsigned short* __restrict__ W2t,  // [5][1024] bf16
    float* __restrict__ out,                 // [M][5] f32, pre-init to b2
    int M)
{
    __shared__ unsigned short As[2][BM * BK];   // 16 KB per buffer
    __shared__ unsigned short Bs[2][BN * BK];

    const int tid  = threadIdx.x;
    const int wv   = tid >> 6;
    const int lane = tid & 63;
    const int bm   = blockIdx.y * BM;
    const int bn   = blockIdx.x * BN;
    const int wr   = (wv & 1) * 64;
    const int wc   = (wv >> 1) * 64;

    f32x4 acc[4][4] = {};

    auto stage = [&](int buf, int k0) {
        // each tile: 128 rows x 128 B = 1024 16B-chunks -> 4 instr/wave/matrix
        #pragma unroll
        for (int j = 0; j < 4; ++j) {
            const int ci  = (wv * 4 + j) * 64 + lane;
            const int row = ci >> 3, c = ci & 7;
            __builtin_amdgcn_global_load_lds(
                A + (size_t)(bm + row) * KPAD + k0 + c * 8,
                &As[buf][(wv * 4 + j) * 512], 16, 0, 0);
        }
        #pragma unroll
        for (int j = 0; j < 4; ++j) {
            const int ci  = (wv * 4 + j) * 64 + lane;
            const int row = ci >> 3, c = ci & 7;
            __builtin_amdgcn_global_load_lds(
                Bt + (size_t)(bn + row) * KPAD + k0 + c * 8,
                &Bs[buf][(wv * 4 + j) * 512], 16, 0, 0);
        }
    };

    stage(0, 0);
    int cur = 0;
    const int q = lane >> 4, r16 = lane & 15;

    #pragma unroll 1
    for (int it = 0; it < KPAD / BK; ++it) {
        __syncthreads();                           // drains prev stage (vmcnt 0)
        if (it + 1 < KPAD / BK) stage(cur ^ 1, (it + 1) * BK);

        #pragma unroll
        for (int ks = 0; ks < BK; ks += 32) {
            bf16x8 af[4], bfr[4];
            #pragma unroll
            for (int mi = 0; mi < 4; ++mi)
                af[mi] = *(const bf16x8*)&As[cur][(wr + mi * 16 + r16) * BK + ks + q * 8];
            #pragma unroll
            for (int nj = 0; nj < 4; ++nj)
                bfr[nj] = *(const bf16x8*)&Bs[cur][(wc + nj * 16 + r16) * BK + ks + q * 8];
            #pragma unroll
            for (int mi = 0; mi < 4; ++mi)
                #pragma unroll
                for (int nj = 0; nj < 4; ++nj)
                    acc[mi][nj] = __builtin_amdgcn_mfma_f32_16x16x32_bf16(
                        af[mi], bfr[nj], acc[mi][nj], 0, 0, 0);
        }
        cur ^= 1;
    }

    // ---- fused epilogue: h -> partial logits ----
    // C/D layout: col(n) = r16, row(m) = q*4 + reg (+ mi*16).
    float bv[4], w2v[4][NCLS];
    #pragma unroll
    for (int nj = 0; nj < 4; ++nj) {
        const int n = bn + wc + nj * 16 + r16;
        if (n < HIDDEN) {
            bv[nj] = bias[n];
            #pragma unroll
            for (int c = 0; c < NCLS; ++c) w2v[nj][c] = bf2f(W2t[c * 1024 + n]);
        } else {
            bv[nj] = 0.f;
            #pragma unroll
            for (int c = 0; c < NCLS; ++c) w2v[nj][c] = 0.f;
        }
    }

    __syncthreads();                     // LDS reuse: As becomes float scratch
    float* pl = (float*)As;              // [4 waves][64 rows][5] = 5120 B

    #pragma unroll
    for (int mi = 0; mi < 4; ++mi) {
        #pragma unroll
        for (int r = 0; r < 4; ++r) {
            float p[NCLS] = {0.f, 0.f, 0.f, 0.f, 0.f};
            #pragma unroll
            for (int nj = 0; nj < 4; ++nj) {
                float h = fmaxf(acc[mi][nj][r] + bv[nj], 0.f);
                #pragma unroll
                for (int c = 0; c < NCLS; ++c) p[c] += h * w2v[nj][c];
            }
            #pragma unroll
            for (int off = 1; off < 16; off <<= 1)
                #pragma unroll
                for (int c = 0; c < NCLS; ++c)
                    p[c] += __shfl_xor(p[c], off, 64);
            if (r16 == 0) {
                const int lr = mi * 16 + q * 4 + r;          // 0..63 in wave tile
                #pragma unroll
                for (int c = 0; c < NCLS; ++c)
                    pl[(wv * 64 + lr) * NCLS + c] = p[c];
            }
        }
    }
    __syncthreads();

    // combine wave pairs (0+2 -> rows 0..63, 1+3 -> rows 64..127), atomic out.
    for (int e = tid; e < BM * NCLS; e += 256) {
        const int lr = e / NCLS, c = e - lr * NCLS;
        float v;
        if (lr < 64) v = pl[(0 * 64 + lr)      * NCLS + c] + pl[(2 * 64 + lr)      * NCLS + c];
        else         v = pl[(1 * 64 + lr - 64) * NCLS + c] + pl[(3 * 64 + lr - 64) * NCLS + c];
        atomicAdd(out + (size_t)(bm + lr) * NCLS + c, v);
    }
}

// ---------------------------------------------------------------------------
extern "C" void kernel_launch(void* const* d_in, const int* in_sizes, int n_in,
                              void* d_out, int out_size, void* d_ws, size_t ws_size,
                              hipStream_t stream)
{
    const int*   x       = (const int*)d_in[0];
    const int*   lengths = (const int*)d_in[1];
    const float* emb     = (const float*)d_in[2];
    const float* W1      = (const float*)d_in[3];
    const float* b1      = (const float*)d_in[4];
    const float* W2      = (const float*)d_in[5];
    const float* b2      = (const float*)d_in[6];
    float*       out     = (float*)d_out;

    const int B = in_sizes[1];               // 4096

    unsigned short* rep  = (unsigned short*)d_ws;         // [B][640]
    unsigned short* w1t  = rep + (size_t)B * KPAD;        // [1024][640]
    unsigned short* w2t  = w1t + (size_t)NPAD * KPAD;     // [5][1024]
    unsigned short* embb = w2t + (size_t)NCLS * 1024;     // [50000][320]

    const size_t need = ((size_t)B * KPAD + (size_t)NPAD * KPAD + NCLS * 1024
                         + (size_t)VOCAB_SZ * EMBPAD) * 2;

    const bool useBf16  = (ws_size >= need);
    const int  embBlks  = useBf16 ? EMB_BLOCKS : 0;
    const int  outBlks  = (B * NCLS + 255) / 256;

    prep_all<<<embBlks + 660 + outBlks, 256, 0, stream>>>(
        emb, embb, W1, w1t, W2, w2t, b2, out, B, embBlks);

    if (useBf16) {
        pool_bf16<<<B, 128, 0, stream>>>(x, lengths, embb, rep);
    } else {
        pool_f32<<<B, 128, 0, stream>>>(x, lengths, emb, rep);
    }

    dim3 g1(NPAD / BN, B / BM);              // (8, 32) = 256 blocks, 1/CU
    gemm1p<<<g1, 256, 0, stream>>>(rep, w1t, b1, w2t, out, B);
}